// Round 9
// baseline (309.639 us; speedup 1.0000x reference)
//
#include <hip/hip_runtime.h>
#include <hip/hip_bf16.h>
#include <math.h>

typedef __hip_bfloat16 bf16;
typedef __attribute__((ext_vector_type(4))) float f32x4;
typedef __attribute__((ext_vector_type(8))) short s16x8;

#define NB 8192
#define KP 1152   // padded K: 1089 -> 18*64
#define NP 1152   // padded N: 1089 -> 9*128

struct SubP {
    const float* x; const float* gamma; const float* beta;
    const float* W1; const float* b1; const float* W2; const float* b2;
    const float* W3; const float* b3;
    float* sum; float* sumsq; float* a; float* b1p; float* hout;
    int F;
};
struct SubP3 { SubP s[3]; };

// ---------------- BatchNorm stats: 64 rows/block, grid (128,3) ----------------
__global__ void __launch_bounds__(256) stats3_kernel(SubP3 P) {
    const SubP p = P.s[blockIdx.z];
    int t = threadIdx.x;
    int row0 = blockIdx.x * 64;
    if (p.F == 1024) {
        f32x4 s = {0.f, 0.f, 0.f, 0.f}, s2 = {0.f, 0.f, 0.f, 0.f};
        const float* xp = p.x + (size_t)row0 * 1024 + t * 4;
        #pragma unroll 8
        for (int r = 0; r < 64; r++) {
            f32x4 v = *(const f32x4*)(xp + (size_t)r * 1024);
            s += v; s2 += v * v;
        }
        int f = t * 4;
        #pragma unroll
        for (int e = 0; e < 4; e++) {
            atomicAdd(&p.sum[f + e], s[e]);
            atomicAdd(&p.sumsq[f + e], s2[e]);
        }
    } else {
        __shared__ float ls[16], ls2[16];
        if (t < 16) { ls[t] = 0.f; ls2[t] = 0.f; }
        __syncthreads();
        int F = p.F;
        for (int idx = t; idx < 64 * F; idx += 256) {
            float v = p.x[(size_t)row0 * F + idx];
            int f = idx % 10;            // row0*F ≡ 0 (mod F)
            atomicAdd(&ls[f], v);
            atomicAdd(&ls2[f], v * v);
        }
        __syncthreads();
        if (t < F) { atomicAdd(&p.sum[t], ls[t]); atomicAdd(&p.sumsq[t], ls2[t]); }
    }
}

// ---------------- finalize stats: a[f]; partial c@W1 fold -> atomic b1p ----------------
__global__ void prep3_kernel(SubP3 P) {
    const SubP p = P.s[blockIdx.y];
    int f0 = blockIdx.x * 32;
    if (f0 >= p.F) return;
    int t = threadIdx.x;
    __shared__ float c_sh[32];
    __shared__ float red[8][33];
    int fc = p.F - f0; if (fc > 32) fc = 32;
    if (t < 32) {
        float c = 0.f;
        if (t < fc) {
            int f = f0 + t;
            float mu  = p.sum[f]   * (1.f / 8192.f);
            float var = p.sumsq[f] * (1.f / 8192.f) - mu * mu;
            float a = p.gamma[f] * rsqrtf(var + 1e-5f);
            p.a[f] = a;
            c = p.beta[f] - mu * a;
        }
        c_sh[t] = c;
    }
    __syncthreads();
    int h = t & 31, g = t >> 5;
    float s = 0.f;
    for (int fi = g; fi < fc; fi += 8)
        s += c_sh[fi] * p.W1[(size_t)(f0 + fi) * 32 + h];
    red[g][h] = s;
    __syncthreads();
    if (t < 32) {
        float tot = 0.f;
        #pragma unroll
        for (int gg = 0; gg < 8; gg++) tot += red[gg][t];
        atomicAdd(&p.b1p[t], tot);
    }
}

// ---------------- Subnet MLP: 32 rows/block, 4h x 8r tile, k-split 8 ----------------
__global__ void __launch_bounds__(256) subnet3_kernel(SubP3 P) {
    const SubP p = P.s[blockIdx.y];
    const int F = p.F;
    __shared__ float smem[8832];
    float* Red = smem;            // 3 x [32][36] = 3456
    float* H1  = smem + 3456;     // [32][36] -> 4608
    float* W23 = smem + 4608;     // [32][33] -> 5664
    float* H2  = smem;            // [32][36]

    int t = threadIdx.x;
    int row0 = blockIdx.x * 32;
    int kg = t >> 6;
    int lane = t & 63;
    int hg = lane & 7, h0 = hg * 4;
    int rg = (lane >> 3) & 3;
    int ks = lane >> 5;

    float acc[4][8] = {};         // [hi][ri], rows rg + 4*ri

    if (F == 1024) {
        float* Xt = smem;             // [32][132] = 4224
        float* Wt = smem + 4224;      // [128][36] = 4608 -> 8832
        int xr = t >> 3, xc = (t & 7) * 16;
        int wk = t >> 1, wh = (t & 1) * 16;
        const float* xbase = p.x + (size_t)row0 * 1024;
        f32x4 xp[4], wp[4]; float av;
        #pragma unroll
        for (int i = 0; i < 4; i++) xp[i] = *(const f32x4*)&xbase[(size_t)xr * 1024 + xc + i * 4];
        #pragma unroll
        for (int i = 0; i < 4; i++) wp[i] = *(const f32x4*)&p.W1[(size_t)wk * 32 + wh + i * 4];
        av = p.a[wk];
        int kb = (kg * 2 + ks) * 16;
        for (int c = 0; c < 8; c++) {
            __syncthreads();          // prev chunk's reads done
            #pragma unroll
            for (int i = 0; i < 4; i++) *(f32x4*)&Xt[xr * 132 + xc + i * 4] = xp[i];
            #pragma unroll
            for (int i = 0; i < 4; i++) *(f32x4*)&Wt[wk * 36 + wh + i * 4] = wp[i] * av;
            if (c < 7) {
                int k0 = (c + 1) * 128;
                #pragma unroll
                for (int i = 0; i < 4; i++) xp[i] = *(const f32x4*)&xbase[(size_t)xr * 1024 + k0 + xc + i * 4];
                #pragma unroll
                for (int i = 0; i < 4; i++) wp[i] = *(const f32x4*)&p.W1[(size_t)(k0 + wk) * 32 + wh + i * 4];
                av = p.a[k0 + wk];
            }
            __syncthreads();          // tiles ready
            #pragma unroll
            for (int s = 0; s < 4; s++) {
                int kk = kb + s * 4;
                f32x4 wv[4], xv[8];
                #pragma unroll
                for (int j = 0; j < 4; j++)  wv[j]  = *(const f32x4*)&Wt[(kk + j) * 36 + h0];
                #pragma unroll
                for (int ri = 0; ri < 8; ri++) xv[ri] = *(const f32x4*)&Xt[(rg + 4 * ri) * 132 + kk];
                #pragma unroll
                for (int j = 0; j < 4; j++)
                    #pragma unroll
                    for (int hi = 0; hi < 4; hi++) {
                        float w = wv[j][hi];
                        #pragma unroll
                        for (int ri = 0; ri < 8; ri++)
                            acc[hi][ri] = fmaf(w, xv[ri][j], acc[hi][ri]);
                    }
            }
        }
    } else {
        float* Xt = smem;             // [32][68]
        float* Wt = smem + 2176;      // [64][36]
        int kbase = (kg * 2 + ks) * 8;
        for (int k0 = 0; k0 < F; k0 += 64) {
            int kc = F - k0; if (kc > 64) kc = 64;
            int kcp = (kc + 3) & ~3;
            __syncthreads();
            for (int idx = t; idx < 32 * kcp; idx += 256) {
                int r = idx / kcp, kk = idx - r * kcp;
                Xt[r * 68 + kk] = (kk < kc) ? p.x[(size_t)(row0 + r) * F + k0 + kk] : 0.f;
            }
            for (int idx = t; idx < kcp * 32; idx += 256) {
                int kk = idx >> 5, hh = idx & 31;
                Wt[kk * 36 + hh] = (kk < kc) ? p.a[k0 + kk] * p.W1[(size_t)(k0 + kk) * 32 + hh] : 0.f;
            }
            __syncthreads();
            #pragma unroll
            for (int s = 0; s < 2; s++) {
                int kk = kbase + s * 4;
                if (kk < kcp) {
                    f32x4 wv[4], xv[8];
                    #pragma unroll
                    for (int j = 0; j < 4; j++)  wv[j]  = *(const f32x4*)&Wt[(kk + j) * 36 + h0];
                    #pragma unroll
                    for (int ri = 0; ri < 8; ri++) xv[ri] = *(const f32x4*)&Xt[(rg + 4 * ri) * 68 + kk];
                    #pragma unroll
                    for (int j = 0; j < 4; j++)
                        #pragma unroll
                        for (int hi = 0; hi < 4; hi++) {
                            float w = wv[j][hi];
                            #pragma unroll
                            for (int ri = 0; ri < 8; ri++)
                                acc[hi][ri] = fmaf(w, xv[ri][j], acc[hi][ri]);
                        }
                }
            }
        }
    }
    // merge the two lane-half k-slices in-register
    #pragma unroll
    for (int hi = 0; hi < 4; hi++)
        #pragma unroll
        for (int ri = 0; ri < 8; ri++)
            acc[hi][ri] += __shfl_xor(acc[hi][ri], 32);
    __syncthreads();                              // S1: Xt/Wt dead
    if (kg > 0 && ks == 0) {
        #pragma unroll
        for (int ri = 0; ri < 8; ri++) {
            int r = rg + 4 * ri;
            f32x4 v = {acc[0][ri], acc[1][ri], acc[2][ri], acc[3][ri]};
            *(f32x4*)&Red[(kg - 1) * 1152 + r * 36 + h0] = v;
        }
    }
    for (int idx = t; idx < 1024; idx += 256) W23[(idx >> 5) * 33 + (idx & 31)] = p.W2[idx];
    __syncthreads();                              // S2: Red + W2 ready
    if (kg == 0 && ks == 0) {
        f32x4 b;
        #pragma unroll
        for (int hi = 0; hi < 4; hi++) b[hi] = p.b1[h0 + hi] + p.b1p[h0 + hi];
        #pragma unroll
        for (int ri = 0; ri < 8; ri++) {
            int r = rg + 4 * ri;
            f32x4 v = {acc[0][ri], acc[1][ri], acc[2][ri], acc[3][ri]};
            #pragma unroll
            for (int pp = 0; pp < 3; pp++)
                v += *(const f32x4*)&Red[pp * 1152 + r * 36 + h0];
            v += b;
            #pragma unroll
            for (int hi = 0; hi < 4; hi++)
                H1[r * 36 + h0 + hi] = fmaxf(v[hi], 0.f);
        }
    }
    __syncthreads();                              // S3: H1 ready
    int h = t & 31, rq = t >> 5;                  // 8 groups x 4 rows
    {
        float a2[4] = {};
        for (int q = 0; q < 32; q++) {
            float w = W23[q * 33 + h];
            #pragma unroll
            for (int i = 0; i < 4; i++) a2[i] += H1[(rq * 4 + i) * 36 + q] * w;
        }
        float bv = p.b2[h];
        #pragma unroll
        for (int i = 0; i < 4; i++) H2[(rq * 4 + i) * 36 + h] = fmaxf(a2[i] + bv, 0.f);
    }
    __syncthreads();                              // S4
    for (int idx = t; idx < 1024; idx += 256) W23[(idx >> 5) * 33 + (idx & 31)] = p.W3[idx];
    __syncthreads();                              // S5
    {
        float a3[4] = {};
        for (int q = 0; q < 32; q++) {
            float w = W23[q * 33 + h];
            #pragma unroll
            for (int i = 0; i < 4; i++) a3[i] += H2[(rq * 4 + i) * 36 + q] * w;
        }
        float bv = p.b3[h];
        #pragma unroll
        for (int i = 0; i < 4; i++)
            p.hout[(size_t)(row0 + rq * 4 + i) * 32 + h] = fmaxf(a3[i] + bv, 0.f);
    }
}

// ---------------- p1 build + W2t transpose (incl. K-pad zeroing), one launch ----------------
__global__ void build_both(const float* __restrict__ mk_h, const float* __restrict__ us_h,
                           bf16* __restrict__ p1,
                           const float* __restrict__ Wf1, bf16* __restrict__ W2t) {
    int blk = blockIdx.x;
    int t = threadIdx.x;
    if (blk < NB) {
        int b = blk;
        __shared__ float mk1[33], us1[33];
        if (t == 0) { mk1[0] = 1.f; us1[0] = 1.f; }
        if (t < 32) mk1[t + 1] = mk_h[(size_t)b * 32 + t];
        else if (t < 64) us1[t - 31] = us_h[(size_t)b * 32 + (t - 32)];
        __syncthreads();
        if (t < 144) {
            int base = t * 8;
            s16x8 v;
            #pragma unroll
            for (int e = 0; e < 8; e++) {
                int idx = base + e;
                float val = 0.f;
                if (idx < 1089) {
                    int k = idx / 33, i = idx - k * 33;
                    val = mk1[k] * us1[i];
                }
                __hip_bfloat16 hb = __float2bfloat16(val);
                v[e] = *(short*)&hb;
            }
            *(s16x8*)(p1 + (size_t)b * KP + base) = v;
        }
    } else {
        int kj = blk - NB;
        int k = kj / 33, j = kj - k * 33;
        __shared__ float tile[1089];
        const float* src = Wf1 + (size_t)k * 35937 + (size_t)j * 1089;  // [i][o] contiguous
        for (int idx = t; idx < 1089; idx += 192) tile[idx] = src[idx];
        __syncthreads();
        for (int idx = t; idx < 1089; idx += 192) {
            int o = idx / 33, i = idx - o * 33;
            W2t[(size_t)(j * 33 + o) * KP + k * 33 + i] = __float2bfloat16(tile[i * 33 + o]);
        }
        if (k == 0) {
            // zero the K-pad (kk 1089..1151) for this j's 33 n-rows
            bf16 z = __float2bfloat16(0.f);
            for (int idx = t; idx < 33 * 63; idx += 192) {
                int o = idx / 63, kkp = 1089 + idx - o * 63;
                W2t[(size_t)(j * 33 + o) * KP + kkp] = z;
            }
        }
    }
}

// ---------------- Main GEMM v3: BM=64, BN=128, BK=64; A via dbuf-LDS (swizzled),
// B direct global->VGPR with 1-iter register prefetch (W2t is L1/L2-resident).
// One barrier per K-iter; the compiler's vmcnt(0)-before-barrier drains loads
// issued a full compute phase earlier.
__global__ void __launch_bounds__(256) gemm_kernel(const bf16* __restrict__ A,   // [NB][KP]
                                                   const bf16* __restrict__ Bt,  // [NP][KP]
                                                   bf16* __restrict__ S) {       // [NB][NP]
    __shared__ __align__(16) bf16 As[2][64 * 64];
    int t = threadIdx.x;
    int m0 = blockIdx.x * 64;
    int n0 = blockIdx.y * 128;
    int wave = t >> 6, lane = t & 63;
    int wm = (wave & 1) * 32, wn = (wave >> 1) * 64;
    int fr = lane & 15;
    int kgi = lane >> 4;            // 0..3

    // A staging mapping: lane l -> row srow, swizzled chunk sc; LDS pos = lane (sequential)
    int srow = lane >> 3;
    int sc = (lane & 7) ^ srow;
    const bf16* Ag = A + (size_t)(m0 + srow) * KP + sc * 8;
    // B fragment base: row n0+wn+fr, chunk kgi
    const bf16* Bg = Bt + (size_t)(n0 + wn + fr) * KP + kgi * 8;

    f32x4 acc[2][4] = {};
    s16x8 Bq[2][8];                 // [buf][nt*2+h]

    auto stageA = [&](int it, int buf) {
        #pragma unroll
        for (int i = 0; i < 2; i++) {
            int rbase = wave * 16 + i * 8;
            __builtin_amdgcn_global_load_lds(
                (const __attribute__((address_space(1))) void*)(Ag + (size_t)rbase * KP + it * 64),
                (__attribute__((address_space(3))) void*)(As[buf] + rbase * 64), 16, 0, 0);
        }
    };
    auto loadB = [&](int it, int buf) {
        #pragma unroll
        for (int nt = 0; nt < 4; nt++)
            #pragma unroll
            for (int h = 0; h < 2; h++)
                Bq[buf][nt * 2 + h] = *(const s16x8*)(Bg + (size_t)(nt * 16) * KP + it * 64 + h * 32);
    };
    auto compute = [&](int buf) {
        #pragma unroll
        for (int h = 0; h < 2; h++) {
            int pofs = ((h * 4 + kgi) ^ (fr & 7)) * 8;
            s16x8 af[2];
            #pragma unroll
            for (int mt = 0; mt < 2; mt++)
                af[mt] = *(const s16x8*)(As[buf] + (wm + mt * 16 + fr) * 64 + pofs);
            #pragma unroll
            for (int mt = 0; mt < 2; mt++)
                #pragma unroll
                for (int nt = 0; nt < 4; nt++)
                    acc[mt][nt] = __builtin_amdgcn_mfma_f32_16x16x32_bf16(
                        af[mt], Bq[buf][nt * 2 + h], acc[mt][nt], 0, 0, 0);
        }
    };

    stageA(0, 0);
    loadB(0, 0);
    for (int it = 0; it < 18; it += 2) {
        __syncthreads();                      // As[0] (it) ready across waves
        if (it + 1 < 18) { stageA(it + 1, 1); loadB(it + 1, 1); }
        compute(0);
        __syncthreads();                      // As[1] (it+1) ready
        if (it + 2 < 18) { stageA(it + 2, 0); loadB(it + 2, 0); }
        compute(1);
    }

    int col = lane & 15, rowg = (lane >> 4) * 4;
    #pragma unroll
    for (int mt = 0; mt < 2; mt++)
        #pragma unroll
        for (int nt = 0; nt < 4; nt++)
            #pragma unroll
            for (int r = 0; r < 4; r++) {
                int gr = m0 + wm + mt * 16 + rowg + r;
                int gc = n0 + wn + nt * 16 + col;
                S[(size_t)gr * NP + gc] = __float2bfloat16(acc[mt][nt][r]);
            }
}

// ---------------- Epilogue: stage S rows as bf16 in LDS, contract j, 33x5 + sigmoid ----------
__global__ void __launch_bounds__(256) epilogue_kernel(const bf16* __restrict__ S,
                                const float* __restrict__ cd_h,
                                const float* __restrict__ bf1, const float* __restrict__ Wf2,
                                const float* __restrict__ bf2, float* __restrict__ out) {
    int w = threadIdx.x >> 6;
    int lane = threadIdx.x & 63;
    int b = blockIdx.x * 4 + w;
    __shared__ __align__(16) unsigned short Sl[4][1152];
    __shared__ float cdsh[4][33];
    __shared__ float hsh[4][40];
    const bf16* Srow = S + (size_t)b * NP;
    #pragma unroll
    for (int pass = 0; pass < 3; pass++) {
        int idx = lane + pass * 64;
        if (idx < 144)
            *(s16x8*)&Sl[w][idx * 8] = *(const s16x8*)(Srow + idx * 8);
    }
    if (lane == 0) cdsh[w][0] = 1.f;
    if (lane < 32) cdsh[w][lane + 1] = cd_h[(size_t)b * 32 + lane];
    __syncthreads();
    if (lane < 33) {
        float acc = bf1[lane];
        #pragma unroll 3
        for (int j = 0; j < 33; j++) {
            unsigned short sv = Sl[w][j * 33 + lane];
            acc += cdsh[w][j] * __bfloat162float(*(bf16*)&sv);
        }
        hsh[w][lane] = fmaxf(acc, 0.f);
    }
    __syncthreads();
    if (lane < 5) {
        float o = bf2[lane];
        for (int q = 0; q < 33; q++) o += hsh[w][q] * Wf2[q * 5 + lane];
        out[(size_t)b * 5 + lane] = 1.f / (1.f + expf(-o));
    }
}

extern "C" void kernel_launch(void* const* d_in, const int* in_sizes, int n_in,
                              void* d_out, int out_size, void* d_ws, size_t ws_size,
                              hipStream_t stream) {
    const float* US_x     = (const float*)d_in[0];
    const float* CDFI_x   = (const float*)d_in[1];
    const float* marker_x = (const float*)d_in[2];
    const float* Wf1      = (const float*)d_in[27];
    const float* bf1      = (const float*)d_in[28];
    const float* Wf2      = (const float*)d_in[29];
    const float* bf2      = (const float*)d_in[30];
    float* out = (float*)d_out;

    char* ws = (char*)d_ws;
    size_t off = 0;
    auto alloc = [&](size_t bytes) -> void* {
        void* p = ws + off;
        off = (off + bytes + 255) & ~(size_t)255;
        return p;
    };

    // per subnet: sum[1024] | sumsq[1024] | b1p_acc[128]  (all zeroed)
    float* stat_big = (float*)alloc(3 * 2176 * sizeof(float));
    float* a_buf[3], *h_buf[3];
    for (int i = 0; i < 3; i++) {
        a_buf[i] = (float*)alloc(1024 * 4);
        h_buf[i] = (float*)alloc((size_t)NB * 32 * 4);
    }
    bf16*  p1   = (bf16*)alloc((size_t)NB * KP * 2);
    bf16*  W2t  = (bf16*)alloc((size_t)NP * KP * 2);
    bf16*  S    = (bf16*)alloc((size_t)NB * NP * 2);

    SubP3 P;
    const float* xs[3] = {US_x, CDFI_x, marker_x};
    int Fs[3] = {1024, 1024, 10};
    for (int i = 0; i < 3; i++) {
        int base = 3 + i * 8;
        P.s[i].x     = xs[i];
        P.s[i].gamma = (const float*)d_in[base + 0];
        P.s[i].beta  = (const float*)d_in[base + 1];
        P.s[i].W1    = (const float*)d_in[base + 2];
        P.s[i].b1    = (const float*)d_in[base + 3];
        P.s[i].W2    = (const float*)d_in[base + 4];
        P.s[i].b2    = (const float*)d_in[base + 5];
        P.s[i].W3    = (const float*)d_in[base + 6];
        P.s[i].b3    = (const float*)d_in[base + 7];
        P.s[i].sum   = stat_big + i * 2176;
        P.s[i].sumsq = stat_big + i * 2176 + 1024;
        P.s[i].b1p   = stat_big + i * 2176 + 2048;
        P.s[i].a     = a_buf[i];
        P.s[i].hout  = h_buf[i];
        P.s[i].F     = Fs[i];
    }

    float* us_h = h_buf[0];
    float* cd_h = h_buf[1];
    float* mk_h = h_buf[2];

    hipMemsetAsync(stat_big, 0, 3 * 2176 * sizeof(float), stream);

    stats3_kernel<<<dim3(128, 1, 3), 256, 0, stream>>>(P);
    prep3_kernel<<<dim3(32, 3), 256, 0, stream>>>(P);
    subnet3_kernel<<<dim3(256, 3), 256, 0, stream>>>(P);

    build_both<<<NB + 1089, 192, 0, stream>>>(mk_h, us_h, p1, Wf1, W2t);

    gemm_kernel<<<dim3(128, 9), 256, 0, stream>>>(p1, W2t, S);

    epilogue_kernel<<<NB / 4, 256, 0, stream>>>(S, cd_h, bf1, Wf2, bf2, out);
}

// Round 10
// 261.871 us; speedup vs baseline: 1.1824x; 1.1824x over previous
//
#include <hip/hip_runtime.h>
#include <hip/hip_bf16.h>
#include <math.h>

typedef __hip_bfloat16 bf16;
typedef __attribute__((ext_vector_type(4))) float f32x4;
typedef __attribute__((ext_vector_type(8))) short s16x8;

#define NB 8192
#define KP 1152   // padded K: 1089 -> 36*32
#define NP 1152   // padded N: 1089 -> 9*128

struct SubP {
    const float* x; const float* gamma; const float* beta;
    const float* W1; const float* b1; const float* W2; const float* b2;
    const float* W3; const float* b3;
    float* sum; float* sumsq; float* a; float* b1p; float* hout;
    int F;
};
struct SubP3 { SubP s[3]; };

// ---------------- BatchNorm stats: 64 rows/block, grid (128,3) ----------------
__global__ void __launch_bounds__(256) stats3_kernel(SubP3 P) {
    const SubP p = P.s[blockIdx.z];
    int t = threadIdx.x;
    int row0 = blockIdx.x * 64;
    if (p.F == 1024) {
        f32x4 s = {0.f, 0.f, 0.f, 0.f}, s2 = {0.f, 0.f, 0.f, 0.f};
        const float* xp = p.x + (size_t)row0 * 1024 + t * 4;
        #pragma unroll 8
        for (int r = 0; r < 64; r++) {
            f32x4 v = *(const f32x4*)(xp + (size_t)r * 1024);
            s += v; s2 += v * v;
        }
        int f = t * 4;
        #pragma unroll
        for (int e = 0; e < 4; e++) {
            atomicAdd(&p.sum[f + e], s[e]);
            atomicAdd(&p.sumsq[f + e], s2[e]);
        }
    } else {
        __shared__ float ls[16], ls2[16];
        if (t < 16) { ls[t] = 0.f; ls2[t] = 0.f; }
        __syncthreads();
        int F = p.F;
        for (int idx = t; idx < 64 * F; idx += 256) {
            float v = p.x[(size_t)row0 * F + idx];
            int f = idx % 10;            // row0*F ≡ 0 (mod F)
            atomicAdd(&ls[f], v);
            atomicAdd(&ls2[f], v * v);
        }
        __syncthreads();
        if (t < F) { atomicAdd(&p.sum[t], ls[t]); atomicAdd(&p.sumsq[t], ls2[t]); }
    }
}

// ---------------- finalize stats: a[f]; partial c@W1 fold -> atomic b1p ----------------
__global__ void prep3_kernel(SubP3 P) {
    const SubP p = P.s[blockIdx.y];
    int f0 = blockIdx.x * 32;
    if (f0 >= p.F) return;
    int t = threadIdx.x;
    __shared__ float c_sh[32];
    __shared__ float red[8][33];
    int fc = p.F - f0; if (fc > 32) fc = 32;
    if (t < 32) {
        float c = 0.f;
        if (t < fc) {
            int f = f0 + t;
            float mu  = p.sum[f]   * (1.f / 8192.f);
            float var = p.sumsq[f] * (1.f / 8192.f) - mu * mu;
            float a = p.gamma[f] * rsqrtf(var + 1e-5f);
            p.a[f] = a;
            c = p.beta[f] - mu * a;
        }
        c_sh[t] = c;
    }
    __syncthreads();
    int h = t & 31, g = t >> 5;
    float s = 0.f;
    for (int fi = g; fi < fc; fi += 8)
        s += c_sh[fi] * p.W1[(size_t)(f0 + fi) * 32 + h];
    red[g][h] = s;
    __syncthreads();
    if (t < 32) {
        float tot = 0.f;
        #pragma unroll
        for (int gg = 0; gg < 8; gg++) tot += red[gg][t];
        atomicAdd(&p.b1p[t], tot);
    }
}

// ---------------- Subnet MLP: 32 rows/block, 4h x 8r tile, k-split 8 ----------------
__global__ void __launch_bounds__(256) subnet3_kernel(SubP3 P) {
    const SubP p = P.s[blockIdx.y];
    const int F = p.F;
    __shared__ float smem[8832];
    float* Red = smem;            // 3 x [32][36] = 3456
    float* H1  = smem + 3456;     // [32][36] -> 4608
    float* W23 = smem + 4608;     // [32][33] -> 5664
    float* H2  = smem;            // [32][36]

    int t = threadIdx.x;
    int row0 = blockIdx.x * 32;
    int kg = t >> 6;
    int lane = t & 63;
    int hg = lane & 7, h0 = hg * 4;
    int rg = (lane >> 3) & 3;
    int ks = lane >> 5;

    float acc[4][8] = {};         // [hi][ri], rows rg + 4*ri

    if (F == 1024) {
        float* Xt = smem;             // [32][132] = 4224
        float* Wt = smem + 4224;      // [128][36] = 4608 -> 8832
        int xr = t >> 3, xc = (t & 7) * 16;
        int wk = t >> 1, wh = (t & 1) * 16;
        const float* xbase = p.x + (size_t)row0 * 1024;
        f32x4 xp[4], wp[4]; float av;
        #pragma unroll
        for (int i = 0; i < 4; i++) xp[i] = *(const f32x4*)&xbase[(size_t)xr * 1024 + xc + i * 4];
        #pragma unroll
        for (int i = 0; i < 4; i++) wp[i] = *(const f32x4*)&p.W1[(size_t)wk * 32 + wh + i * 4];
        av = p.a[wk];
        int kb = (kg * 2 + ks) * 16;
        for (int c = 0; c < 8; c++) {
            __syncthreads();          // prev chunk's reads done
            #pragma unroll
            for (int i = 0; i < 4; i++) *(f32x4*)&Xt[xr * 132 + xc + i * 4] = xp[i];
            #pragma unroll
            for (int i = 0; i < 4; i++) *(f32x4*)&Wt[wk * 36 + wh + i * 4] = wp[i] * av;
            if (c < 7) {
                int k0 = (c + 1) * 128;
                #pragma unroll
                for (int i = 0; i < 4; i++) xp[i] = *(const f32x4*)&xbase[(size_t)xr * 1024 + k0 + xc + i * 4];
                #pragma unroll
                for (int i = 0; i < 4; i++) wp[i] = *(const f32x4*)&p.W1[(size_t)(k0 + wk) * 32 + wh + i * 4];
                av = p.a[k0 + wk];
            }
            __syncthreads();          // tiles ready
            #pragma unroll
            for (int s = 0; s < 4; s++) {
                int kk = kb + s * 4;
                f32x4 wv[4], xv[8];
                #pragma unroll
                for (int j = 0; j < 4; j++)  wv[j]  = *(const f32x4*)&Wt[(kk + j) * 36 + h0];
                #pragma unroll
                for (int ri = 0; ri < 8; ri++) xv[ri] = *(const f32x4*)&Xt[(rg + 4 * ri) * 132 + kk];
                #pragma unroll
                for (int j = 0; j < 4; j++)
                    #pragma unroll
                    for (int hi = 0; hi < 4; hi++) {
                        float w = wv[j][hi];
                        #pragma unroll
                        for (int ri = 0; ri < 8; ri++)
                            acc[hi][ri] = fmaf(w, xv[ri][j], acc[hi][ri]);
                    }
            }
        }
    } else {
        float* Xt = smem;             // [32][68]
        float* Wt = smem + 2176;      // [64][36]
        int kbase = (kg * 2 + ks) * 8;
        for (int k0 = 0; k0 < F; k0 += 64) {
            int kc = F - k0; if (kc > 64) kc = 64;
            int kcp = (kc + 3) & ~3;
            __syncthreads();
            for (int idx = t; idx < 32 * kcp; idx += 256) {
                int r = idx / kcp, kk = idx - r * kcp;
                Xt[r * 68 + kk] = (kk < kc) ? p.x[(size_t)(row0 + r) * F + k0 + kk] : 0.f;
            }
            for (int idx = t; idx < kcp * 32; idx += 256) {
                int kk = idx >> 5, hh = idx & 31;
                Wt[kk * 36 + hh] = (kk < kc) ? p.a[k0 + kk] * p.W1[(size_t)(k0 + kk) * 32 + hh] : 0.f;
            }
            __syncthreads();
            #pragma unroll
            for (int s = 0; s < 2; s++) {
                int kk = kbase + s * 4;
                if (kk < kcp) {
                    f32x4 wv[4], xv[8];
                    #pragma unroll
                    for (int j = 0; j < 4; j++)  wv[j]  = *(const f32x4*)&Wt[(kk + j) * 36 + h0];
                    #pragma unroll
                    for (int ri = 0; ri < 8; ri++) xv[ri] = *(const f32x4*)&Xt[(rg + 4 * ri) * 68 + kk];
                    #pragma unroll
                    for (int j = 0; j < 4; j++)
                        #pragma unroll
                        for (int hi = 0; hi < 4; hi++) {
                            float w = wv[j][hi];
                            #pragma unroll
                            for (int ri = 0; ri < 8; ri++)
                                acc[hi][ri] = fmaf(w, xv[ri][j], acc[hi][ri]);
                        }
                }
            }
        }
    }
    // merge the two lane-half k-slices in-register
    #pragma unroll
    for (int hi = 0; hi < 4; hi++)
        #pragma unroll
        for (int ri = 0; ri < 8; ri++)
            acc[hi][ri] += __shfl_xor(acc[hi][ri], 32);
    __syncthreads();                              // S1: Xt/Wt dead
    if (kg > 0 && ks == 0) {
        #pragma unroll
        for (int ri = 0; ri < 8; ri++) {
            int r = rg + 4 * ri;
            f32x4 v = {acc[0][ri], acc[1][ri], acc[2][ri], acc[3][ri]};
            *(f32x4*)&Red[(kg - 1) * 1152 + r * 36 + h0] = v;
        }
    }
    for (int idx = t; idx < 1024; idx += 256) W23[(idx >> 5) * 33 + (idx & 31)] = p.W2[idx];
    __syncthreads();                              // S2: Red + W2 ready
    if (kg == 0 && ks == 0) {
        f32x4 b;
        #pragma unroll
        for (int hi = 0; hi < 4; hi++) b[hi] = p.b1[h0 + hi] + p.b1p[h0 + hi];
        #pragma unroll
        for (int ri = 0; ri < 8; ri++) {
            int r = rg + 4 * ri;
            f32x4 v = {acc[0][ri], acc[1][ri], acc[2][ri], acc[3][ri]};
            #pragma unroll
            for (int pp = 0; pp < 3; pp++)
                v += *(const f32x4*)&Red[pp * 1152 + r * 36 + h0];
            v += b;
            #pragma unroll
            for (int hi = 0; hi < 4; hi++)
                H1[r * 36 + h0 + hi] = fmaxf(v[hi], 0.f);
        }
    }
    __syncthreads();                              // S3: H1 ready
    int h = t & 31, rq = t >> 5;                  // 8 groups x 4 rows
    {
        float a2[4] = {};
        for (int q = 0; q < 32; q++) {
            float w = W23[q * 33 + h];
            #pragma unroll
            for (int i = 0; i < 4; i++) a2[i] += H1[(rq * 4 + i) * 36 + q] * w;
        }
        float bv = p.b2[h];
        #pragma unroll
        for (int i = 0; i < 4; i++) H2[(rq * 4 + i) * 36 + h] = fmaxf(a2[i] + bv, 0.f);
    }
    __syncthreads();                              // S4
    for (int idx = t; idx < 1024; idx += 256) W23[(idx >> 5) * 33 + (idx & 31)] = p.W3[idx];
    __syncthreads();                              // S5
    {
        float a3[4] = {};
        for (int q = 0; q < 32; q++) {
            float w = W23[q * 33 + h];
            #pragma unroll
            for (int i = 0; i < 4; i++) a3[i] += H2[(rq * 4 + i) * 36 + q] * w;
        }
        float bv = p.b3[h];
        #pragma unroll
        for (int i = 0; i < 4; i++)
            p.hout[(size_t)(row0 + rq * 4 + i) * 32 + h] = fmaxf(a3[i] + bv, 0.f);
    }
}

// ---------------- p1 build + W2t transpose (incl. K-pad zeroing), one launch ----------------
__global__ void build_both(const float* __restrict__ mk_h, const float* __restrict__ us_h,
                           bf16* __restrict__ p1,
                           const float* __restrict__ Wf1, bf16* __restrict__ W2t) {
    int blk = blockIdx.x;
    int t = threadIdx.x;
    if (blk < NB) {
        int b = blk;
        __shared__ float mk1[33], us1[33];
        if (t == 0) { mk1[0] = 1.f; us1[0] = 1.f; }
        if (t < 32) mk1[t + 1] = mk_h[(size_t)b * 32 + t];
        else if (t < 64) us1[t - 31] = us_h[(size_t)b * 32 + (t - 32)];
        __syncthreads();
        if (t < 144) {
            int base = t * 8;
            s16x8 v;
            #pragma unroll
            for (int e = 0; e < 8; e++) {
                int idx = base + e;
                float val = 0.f;
                if (idx < 1089) {
                    int k = idx / 33, i = idx - k * 33;
                    val = mk1[k] * us1[i];
                }
                __hip_bfloat16 hb = __float2bfloat16(val);
                v[e] = *(short*)&hb;
            }
            *(s16x8*)(p1 + (size_t)b * KP + base) = v;
        }
    } else {
        int kj = blk - NB;
        int k = kj / 33, j = kj - k * 33;
        __shared__ float tile[1089];
        const float* src = Wf1 + (size_t)k * 35937 + (size_t)j * 1089;  // [i][o] contiguous
        for (int idx = t; idx < 1089; idx += 192) tile[idx] = src[idx];
        __syncthreads();
        for (int idx = t; idx < 1089; idx += 192) {
            int o = idx / 33, i = idx - o * 33;
            W2t[(size_t)(j * 33 + o) * KP + k * 33 + i] = __float2bfloat16(tile[i * 33 + o]);
        }
        if (k == 0) {
            // zero the K-pad (kk 1089..1151) for this j's 33 n-rows
            bf16 z = __float2bfloat16(0.f);
            for (int idx = t; idx < 33 * 63; idx += 192) {
                int o = idx / 63, kkp = 1089 + idx - o * 63;
                W2t[(size_t)(j * 33 + o) * KP + kkp] = z;
            }
        }
    }
}

// ---------------- Main GEMM v4: BM=64, BN=128, BK=32, both operands via
// global_load_lds, 2-bit XOR swizzle (pos = chunk ^ (row&3)) -> 2-way max
// (free, m136). Grid (128,9) = 1152 blocks for latency hiding.
__global__ void __launch_bounds__(256) gemm_kernel(const bf16* __restrict__ A,   // [NB][KP]
                                                   const bf16* __restrict__ Bt,  // [NP][KP]
                                                   bf16* __restrict__ S) {       // [NB][NP]
    __shared__ __align__(16) bf16 As[64 * 32];
    __shared__ __align__(16) bf16 Bs[128 * 32];
    int t = threadIdx.x;
    int m0 = blockIdx.x * 64;
    int n0 = blockIdx.y * 128;
    int wave = t >> 6, lane = t & 63;
    int wm = (wave & 1) * 32, wn = (wave >> 1) * 64;
    int fr = lane & 15;
    int kgi = lane >> 4;              // 0..3 (16B chunk within BK=32 row)

    // staging: lane covers (row sr, pos sp); fetches global chunk sp^(sr&3)
    int sr = lane >> 2, sp = lane & 3;
    int sc = sp ^ (sr & 3);
    const bf16* AgW = A  + (size_t)(m0 + wave * 16 + sr) * KP + sc * 8;
    const bf16* BgW = Bt + (size_t)(n0 + wave * 32 + sr) * KP + sc * 8;
    bf16* AsW = As + wave * 16 * 32;
    bf16* BsW = Bs + wave * 32 * 32;

    f32x4 acc[2][4] = {};

    for (int k0 = 0; k0 < KP; k0 += 32) {
        __syncthreads();
        __builtin_amdgcn_global_load_lds(
            (const __attribute__((address_space(1))) void*)(AgW + k0),
            (__attribute__((address_space(3))) void*)(AsW), 16, 0, 0);
        __builtin_amdgcn_global_load_lds(
            (const __attribute__((address_space(1))) void*)(BgW + k0),
            (__attribute__((address_space(3))) void*)(BsW), 16, 0, 0);
        __builtin_amdgcn_global_load_lds(
            (const __attribute__((address_space(1))) void*)(BgW + k0 + (size_t)16 * KP),
            (__attribute__((address_space(3))) void*)(BsW + 16 * 32), 16, 0, 0);
        __syncthreads();
        int pofs = (kgi ^ (fr & 3)) * 8;
        s16x8 af[2], bq[4];
        #pragma unroll
        for (int mt = 0; mt < 2; mt++)
            af[mt] = *(const s16x8*)(As + (wm + mt * 16 + fr) * 32 + pofs);
        #pragma unroll
        for (int nt = 0; nt < 4; nt++)
            bq[nt] = *(const s16x8*)(Bs + (wn + nt * 16 + fr) * 32 + pofs);
        #pragma unroll
        for (int mt = 0; mt < 2; mt++)
            #pragma unroll
            for (int nt = 0; nt < 4; nt++)
                acc[mt][nt] = __builtin_amdgcn_mfma_f32_16x16x32_bf16(af[mt], bq[nt], acc[mt][nt], 0, 0, 0);
    }
    int col = lane & 15, rowg = (lane >> 4) * 4;
    #pragma unroll
    for (int mt = 0; mt < 2; mt++)
        #pragma unroll
        for (int nt = 0; nt < 4; nt++)
            #pragma unroll
            for (int r = 0; r < 4; r++) {
                int gr = m0 + wm + mt * 16 + rowg + r;
                int gc = n0 + wn + nt * 16 + col;
                S[(size_t)gr * NP + gc] = __float2bfloat16(acc[mt][nt][r]);
            }
}

// ---------------- Epilogue: stage S rows as bf16 in LDS, contract j, 33x5 + sigmoid ----------
__global__ void __launch_bounds__(256) epilogue_kernel(const bf16* __restrict__ S,
                                const float* __restrict__ cd_h,
                                const float* __restrict__ bf1, const float* __restrict__ Wf2,
                                const float* __restrict__ bf2, float* __restrict__ out) {
    int w = threadIdx.x >> 6;
    int lane = threadIdx.x & 63;
    int b = blockIdx.x * 4 + w;
    __shared__ __align__(16) unsigned short Sl[4][1152];
    __shared__ float cdsh[4][33];
    __shared__ float hsh[4][40];
    const bf16* Srow = S + (size_t)b * NP;
    #pragma unroll
    for (int pass = 0; pass < 3; pass++) {
        int idx = lane + pass * 64;
        if (idx < 144)
            *(s16x8*)&Sl[w][idx * 8] = *(const s16x8*)(Srow + idx * 8);
    }
    if (lane == 0) cdsh[w][0] = 1.f;
    if (lane < 32) cdsh[w][lane + 1] = cd_h[(size_t)b * 32 + lane];
    __syncthreads();
    if (lane < 33) {
        float acc = bf1[lane];
        #pragma unroll 3
        for (int j = 0; j < 33; j++) {
            unsigned short sv = Sl[w][j * 33 + lane];
            acc += cdsh[w][j] * __bfloat162float(*(bf16*)&sv);
        }
        hsh[w][lane] = fmaxf(acc, 0.f);
    }
    __syncthreads();
    if (lane < 5) {
        float o = bf2[lane];
        for (int q = 0; q < 33; q++) o += hsh[w][q] * Wf2[q * 5 + lane];
        out[(size_t)b * 5 + lane] = 1.f / (1.f + expf(-o));
    }
}

extern "C" void kernel_launch(void* const* d_in, const int* in_sizes, int n_in,
                              void* d_out, int out_size, void* d_ws, size_t ws_size,
                              hipStream_t stream) {
    const float* US_x     = (const float*)d_in[0];
    const float* CDFI_x   = (const float*)d_in[1];
    const float* marker_x = (const float*)d_in[2];
    const float* Wf1      = (const float*)d_in[27];
    const float* bf1      = (const float*)d_in[28];
    const float* Wf2      = (const float*)d_in[29];
    const float* bf2      = (const float*)d_in[30];
    float* out = (float*)d_out;

    char* ws = (char*)d_ws;
    size_t off = 0;
    auto alloc = [&](size_t bytes) -> void* {
        void* p = ws + off;
        off = (off + bytes + 255) & ~(size_t)255;
        return p;
    };

    // per subnet: sum[1024] | sumsq[1024] | b1p_acc[128]  (all zeroed)
    float* stat_big = (float*)alloc(3 * 2176 * sizeof(float));
    float* a_buf[3], *h_buf[3];
    for (int i = 0; i < 3; i++) {
        a_buf[i] = (float*)alloc(1024 * 4);
        h_buf[i] = (float*)alloc((size_t)NB * 32 * 4);
    }
    bf16*  p1   = (bf16*)alloc((size_t)NB * KP * 2);
    bf16*  W2t  = (bf16*)alloc((size_t)NP * KP * 2);
    bf16*  S    = (bf16*)alloc((size_t)NB * NP * 2);

    SubP3 P;
    const float* xs[3] = {US_x, CDFI_x, marker_x};
    int Fs[3] = {1024, 1024, 10};
    for (int i = 0; i < 3; i++) {
        int base = 3 + i * 8;
        P.s[i].x     = xs[i];
        P.s[i].gamma = (const float*)d_in[base + 0];
        P.s[i].beta  = (const float*)d_in[base + 1];
        P.s[i].W1    = (const float*)d_in[base + 2];
        P.s[i].b1    = (const float*)d_in[base + 3];
        P.s[i].W2    = (const float*)d_in[base + 4];
        P.s[i].b2    = (const float*)d_in[base + 5];
        P.s[i].W3    = (const float*)d_in[base + 6];
        P.s[i].b3    = (const float*)d_in[base + 7];
        P.s[i].sum   = stat_big + i * 2176;
        P.s[i].sumsq = stat_big + i * 2176 + 1024;
        P.s[i].b1p   = stat_big + i * 2176 + 2048;
        P.s[i].a     = a_buf[i];
        P.s[i].hout  = h_buf[i];
        P.s[i].F     = Fs[i];
    }

    float* us_h = h_buf[0];
    float* cd_h = h_buf[1];
    float* mk_h = h_buf[2];

    hipMemsetAsync(stat_big, 0, 3 * 2176 * sizeof(float), stream);

    stats3_kernel<<<dim3(128, 1, 3), 256, 0, stream>>>(P);
    prep3_kernel<<<dim3(32, 3), 256, 0, stream>>>(P);
    subnet3_kernel<<<dim3(256, 3), 256, 0, stream>>>(P);

    build_both<<<NB + 1089, 192, 0, stream>>>(mk_h, us_h, p1, Wf1, W2t);

    gemm_kernel<<<dim3(128, 9), 256, 0, stream>>>(p1, W2t, S);

    epilogue_kernel<<<NB / 4, 256, 0, stream>>>(S, cd_h, bf1, Wf2, bf2, out);
}